// Round 11
// baseline (740.571 us; speedup 1.0000x reference)
//
#include <hip/hip_runtime.h>
#include <math.h>

#define CAPT 20480              // per-type compacted-node capacity (actual ~16.7k)
#define R2   (2*CAPT)
#define GLD  136                // kgru LDS row stride (ushorts): breaks pow2 banking
#define GRR  32                 // kgru rows per block

typedef __attribute__((ext_vector_type(8))) short short8;
typedef __attribute__((ext_vector_type(4))) float f32x4;

// ---- fast transcendentals: v_exp_f32 / v_rcp_f32 based; err ~1e-7 << bf16 ulp ----
__device__ __forceinline__ float fexp2_(float x){ return __builtin_amdgcn_exp2f(x); }
__device__ __forceinline__ float frcp_(float x){ return __builtin_amdgcn_rcpf(x); }
// tanh(x) = 1 - 2/(1+e^{2x}); overflow-safe: exp2->inf => rcp->0 => 1; underflow => -1.
__device__ __forceinline__ float ftanh_(float x){
  float t = fexp2_(2.885390082f * x);
  return __builtin_fmaf(-2.f, frcp_(1.f + t), 1.f);
}
__device__ __forceinline__ float fsig_(float x){
  return frcp_(1.f + fexp2_(-1.442695041f * x));
}
// exact rewrite of tanh-approx gelu: 0.5x(1+tanh(c(x+0.044715x^3))) == x*sigmoid(2c(x+0.044715x^3))
__device__ __forceinline__ float fgelu_(float x){
  float x2 = x*x;
  float u  = x * __builtin_fmaf(x2, 0.044715f, 1.0f);
  float e  = fexp2_(u * -2.30220818f);
  return x * frcp_(1.f + e);
}
__device__ __forceinline__ unsigned short f2bf(float x){
  unsigned int u = __float_as_uint(x);
  return (unsigned short)((u + 0x7FFFu + ((u>>16)&1u)) >> 16);
}
__device__ __forceinline__ float bf2f(unsigned short v){
  return __uint_as_float(((unsigned int)v) << 16);
}
// packed RNE f32->bf16 pair: 1 inst replaces 2x 5-op manual sequences (same rounding)
__device__ __forceinline__ unsigned int cvt_pk_bf16(float a, float b){
  unsigned int r;
  asm("v_cvt_pk_bf16_f32 %0, %1, %2" : "=v"(r) : "v"(a), "v"(b));
  return r;
}
// async global->LDS DMA, 16B per lane; dest = wave-uniform base + lane*16
__device__ __forceinline__ void gload_lds16(const unsigned short* g, unsigned short* l){
  __builtin_amdgcn_global_load_lds((const __attribute__((address_space(1))) void*)g,
                                   (__attribute__((address_space(3))) void*)l, 16, 0, 0);
}

// ======== k_prep_all v3: ALL independent prep + edge-count + curp-zero in ONE launch =
__global__ void k_prep_all(
    const int* __restrict__ edst, int TE, int* __restrict__ deg,
    const float* __restrict__ Wm_plain, const float* __restrict__ Wu_plain,
    const float* __restrict__ Wm_ar, const float* __restrict__ Wu_ar,
    const float* __restrict__ Wi_map, const float* __restrict__ Wh_map,
    const float* __restrict__ Wi_mem, const float* __restrict__ Wh_mem,
    unsigned short* __restrict__ BtArena,
    const float* __restrict__ bm_plain, const float* __restrict__ bu_plain,
    const float* __restrict__ bm_ar, const float* __restrict__ bu_ar,
    const float* __restrict__ bi_map, const float* __restrict__ bh_map,
    const float* __restrict__ bi_mem, const float* __restrict__ bh_mem,
    float* __restrict__ biasA,
    const float* __restrict__ embed, unsigned short* __restrict__ embB, int V64,
    const int* __restrict__ type_idx, unsigned short* __restrict__ h, int N,
    int* __restrict__ curp,
    int* __restrict__ idxcat, int* __restrict__ cnt)
{
  __shared__ int lc[2];
  __shared__ int lbase[2];
  int t = threadIdx.x;
  int b = blockIdx.x;
  const int BCnt = (TE + 255)/256;
  const int BPB = 18*32;
  const int BE  = (V64/8 + 255)/256;
  const int BH  = (N*10 + 255)/256;
  const int BZ  = (N/4 + 255)/256;
  int e0 = BCnt, e1 = e0 + BPB, e2 = e1 + 1, e3 = e2 + BE, e4 = e3 + BH, e5 = e4 + BZ;

  if (b < e0){
    // ---- role C: edge-count histogram (deg pre-zeroed by memset) ----
    int i = b*256 + t;
    if (i < TE) atomicAdd(&deg[edst[i]], 1);
  } else if (b < e1){
    // ---- role 0: weight arena (id = bb/32, xpart = bb%32) ----
    int bb = b - e0;
    int id = bb >> 5, xpart = bb & 31;
    int Kp, elems, off;
    if (id < 6){ Kp=96;  elems=15360; off=id*15360; }
    else if (id < 12){ Kp=160; elems=12800; off=92160+(id-6)*12800; }
    else if (id < 14){ Kp=160; elems=51200; off=168960+(id-12)*51200; }
    else if (id < 16){ Kp=320; elems=25600; off=271360+(id-14)*25600; }
    else { Kp=128; elems=32768; off=322560+(id-16)*32768; }
    for (int g = xpart*256 + t; g < elems; g += 32*256){
      int c = g / Kp, k = g - c*Kp;
      float val = 0.f;
      if (id < 6){
        int li = id; int tt = (c >= 80); int cc = c - tt*80;
        if (cc < 70 && k < 70) val = Wm_plain[((li*2+tt)*70 + k)*70 + cc];
      } else if (id < 12){
        int li = id-6;
        int kk = (k < 70) ? k : ((k >= 80 && k < 150) ? 70 + (k-80) : -1);
        if (c < 70 && kk >= 0) val = Wu_plain[(li*140 + kk)*70 + c];
      } else if (id < 14){
        int blk = id-12; int tt = (c >= 160); int cc = c - tt*160;
        int kk = (k < 70) ? k : ((k >= 80 && k < 150) ? 70 + (k-80) : -1);
        if (cc < 140 && kk >= 0) val = Wm_ar[(((blk*2+tt)*140) + kk)*140 + cc];
      } else if (id < 16){
        int blk = id-14;
        int kk = (k < 70) ? k : ((k >= 80 && k < 150) ? 70 + (k-80)
                 : ((k >= 160 && k < 300) ? 140 + (k-160) : -1));
        if (c < 70 && kk >= 0) val = Wu_ar[(blk*280 + kk)*70 + c];
      } else {
        int typ = id-16;
        const float* Wi = typ ? Wi_mem : Wi_map;
        const float* Wh = typ ? Wh_mem : Wh_map;
        if (c < 192) val = (k < 64) ? Wi[c*64 + k] : Wh[c*64 + (k-64)];
        else { int cc = c-192; val = (k >= 64) ? Wh[(128+cc)*64 + (k-64)] : 0.f; }
      }
      BtArena[off + g] = f2bf(val);
    }
  } else if (b < e2){
    // ---- role 1: bias arena ----
    for (int g = t; g < 2752; g += 256){
      float val = 0.f;
      if (g < 960){ int li=g/160, c=g%160; int tt=(c>=80); int cc=c-tt*80;
        if (cc<70) val = bm_plain[(li*2+tt)*70 + cc]; }
      else if (g < 1440){ int u=g-960; int li=u/80, c=u%80; if (c<70) val = bu_plain[li*70+c]; }
      else if (g < 2080){ int u=g-1440; int blk=u/320, c=u%320; int tt=(c>=160); int cc=c-tt*160;
        if (cc<140) val = bm_ar[(blk*2+tt)*140 + cc]; }
      else if (g < 2240){ int u=g-2080; int blk=u/80, c=u%80; if (c<70) val = bu_ar[blk*70+c]; }
      else { int u=g-2240; int typ=u/256, c=u%256;
        const float* bi = typ ? bi_mem : bi_map; const float* bh = typ ? bh_mem : bh_map;
        val = (c < 192) ? (bi[c]+bh[c]) : bh[128 + (c-192)]; }
      biasA[g] = val;
    }
  } else if (b < e3){
    // ---- role 2: embed -> bf16, 8 elems/thread ----
    int g = (b - e2)*256 + t;
    if (g < V64/8){
      const float* s = embed + (size_t)g*8;
      unsigned int p0 = cvt_pk_bf16(s[0], s[1]);
      unsigned int p1 = cvt_pk_bf16(s[2], s[3]);
      unsigned int p2 = cvt_pk_bf16(s[4], s[5]);
      unsigned int p3 = cvt_pk_bf16(s[6], s[7]);
      uint4 v = {p0, p1, p2, p3};
      *(uint4*)&embB[(size_t)g*8] = v;
    }
  } else if (b < e4){
    // ---- role 3: init h one-hot, 8 bf16/thread (10 threads per 80-wide row) ----
    int g = (b - e3)*256 + t;
    if (g < N*10){
      int n = g / 10, c0 = (g - n*10)*8;
      unsigned int w0 = 0, w1 = 0, w2 = 0, w3 = 0;
      if (c0 == 0){
        int ty = type_idx[n];
        unsigned int one = 0x3F80u;
        if (ty == 0) w0 |= one;        else if (ty == 1) w0 |= one << 16;
        if (ty == 2) w1 |= one;        else if (ty == 3) w1 |= one << 16;
        if (ty == 4) w2 |= one;        else if (ty == 5) w2 |= one << 16;
      }
      uint4 v = {w0, w1, w2, w3};
      *(uint4*)&h[(size_t)n*80 + c0] = v;
    }
  } else if (b < e5){
    // ---- role 4: zero curp (int4/thread; read only by k_fill, 3 dispatches later) ----
    int g = (b - e4)*256 + t;
    if (g < N/4){
      const int4 z = {0,0,0,0};
      *(int4*)&curp[g*4] = z;
    }
    if (g == 0){
      for (int r = (N/4)*4; r < N; r++) curp[r] = 0;     // tail (N%4)
    }
  } else {
    // ---- role 5: compact, LDS-aggregated (1 global atomic per block per type) ----
    if (t < 2) lc[t] = 0;
    __syncthreads();
    int n = (b - e5)*256 + t;
    int sel = -1, pos = 0;
    if (n < N){
      int ty = type_idx[n];
      if (ty == 0){ sel = 0; pos = atomicAdd(&lc[0], 1); }
      else if (ty == 5){ sel = 1; pos = atomicAdd(&lc[1], 1); }
    }
    __syncthreads();
    if (t < 2) lbase[t] = lc[t] ? atomicAdd(&cnt[t], lc[t]) : 0;
    __syncthreads();
    if (sel >= 0){
      int p = lbase[sel] + pos;
      if (p < CAPT) idxcat[sel*CAPT + p] = n;
    }
  }
}

// ---------------- CSR build: scan1 (per-chunk partial offsets) + scan2 (chunk prefix)
__global__ void k_scan1(const int* __restrict__ deg, int* __restrict__ off,
                        int* __restrict__ bsum, int N){
  __shared__ int sh[256];
  int t = threadIdx.x; int base = blockIdx.x*2048;
  int v[8]; int s = 0;
  for (int i=0;i<8;i++){
    int g = base + t*8 + i;
    int x = (g<N)? (((deg[g]+3)>>2)<<2) : 0;     // pad to x4
    v[i]=x; s+=x;
  }
  sh[t]=s; __syncthreads();
  for (int o=1;o<256;o<<=1){ int x = (t>=o)? sh[t-o]:0; __syncthreads(); sh[t]+=x; __syncthreads(); }
  if (t==255) bsum[blockIdx.x] = sh[255];
  int run = sh[t]-s;
  for (int i=0;i<8;i++){ int g = base + t*8 + i; if (g<N) off[g]=run; run+=v[i]; }
}
// converts bsum to prefix AND closes the last node's range: off[N]+bsum[N>>11] == total
__global__ void k_scan2(int* bsum, int* off, int N, int nb){
  if (threadIdx.x==0 && blockIdx.x==0){
    int run=0;
    for(int b=0;b<nb;b++){ int x=bsum[b]; bsum[b]=run; run+=x; }
    bsum[nb]=run;
    off[N] = run - bsum[N>>11];
  }
}
// fill + SELF-PAD: the thread placing a node's LAST edge writes the pad slots with its
// OWN edge (idempotent for segment-max; messages depend only on (src,type)).
__global__ void k_fill(const int* __restrict__ esrc, const int* __restrict__ edst,
                       const int* __restrict__ off, const int* __restrict__ bsum,
                       const int* __restrict__ deg, int* __restrict__ cur,
                       int* __restrict__ edata, int TE, int E){
  int i = blockIdx.x*256 + threadIdx.x;
  if (i >= TE) return;
  int d = edst[i];
  int pos = atomicAdd(&cur[d], 1);
  int base = off[d] + bsum[d>>11];
  int ev = (esrc[i] << 1) | (i >= E ? 1 : 0);
  edata[base + pos] = ev;
  int dg = deg[d];
  if (pos == dg - 1){
    int d4 = ((dg+3)>>2)<<2;
    for (int k = dg; k < d4; k++) edata[base + k] = ev;
  }
}

// ======== kgru v6: count-based validity (no idxcat sentinel memset needed) ==========
__global__ __launch_bounds__(256) void kgru(
    const int* __restrict__ idxcat, const int* __restrict__ cnt,
    const int* __restrict__ tokens,
    const unsigned short* __restrict__ embB,
    const unsigned short* __restrict__ Bt, const unsigned short* __restrict__ Bt2,
    const float* __restrict__ bias, const float* __restrict__ bias2,
    unsigned short* __restrict__ hOut)
{
  __shared__ __align__(16) unsigned short As[2][GRR*GLD];
  __shared__ int tokS[GRR*8];
  __shared__ int idxS[GRR];
  int nv = cnt[blockIdx.y]; if (nv > CAPT) nv = CAPT;
  int r0 = blockIdx.x * GRR;
  if (r0 >= nv) return;                            // fully-invalid block
  int rb = blockIdx.y * CAPT + r0;
  int t = threadIdx.x;
  int lane = t & 63, m = lane & 15, q = lane >> 4, w = t >> 6;
  const unsigned short* Bsel = blockIdx.y ? Bt2 : Bt;
  const float* bsel = blockIdx.y ? bias2 : bias;
  short8 breg[4][4]; f32x4 bv[4];
  #pragma unroll
  for (int j=0;j<4;j++){
    int col = (w + 4*j)*16 + m;
    bv[j] = *(const f32x4*)&bsel[(w + 4*j)*16 + q*4];   // 16B-aligned float4
    #pragma unroll
    for (int kt=0;kt<4;kt++)
      breg[j][kt] = *(const short8*)&Bsel[(size_t)col*128 + kt*32 + q*8];
  }
  if (t < GRR) idxS[t] = (r0 + t < nv) ? idxcat[rb + t] : -1;
  if (t < GRR*8){
    int r8 = t >> 3;
    int nd = (r0 + r8 < nv) ? idxcat[rb + r8] : 0;
    if (nd < 0) nd = 0;
    tokS[t] = tokens[nd*8 + (t & 7)];
  }
  __syncthreads();                                 // tokS ready
  if (t < GRR*8){
    int row = t >> 3, ch = t & 7;
    *(uint4*)&As[0][row*GLD + ch*8] = *(const uint4*)&embB[(size_t)tokS[row*8]*64 + ch*8];
  }
  for (int j = t; j < GRR*32; j += 256){
    int row = j >> 5, k2 = (j & 31)*2;
    *(unsigned int*)&As[0][row*GLD + 64 + k2] = 0;
  }
  __syncthreads();
  unsigned short hreg[2][4];                       // row m (per rt), cols u4+0..3
  #pragma unroll
  for (int rt=0;rt<2;rt++)
    #pragma unroll
    for (int i=0;i<4;i++) hreg[rt][i] = 0;
  int u4 = w*16 + q*4;                             // col base within H (64 wide)
  int p = 0;
  for (int s = 0; s < 8; s++){
    uint4 xr;
    if (s < 7 && t < GRR*8){                       // prefetch X(s+1) early (global)
      int row = t >> 3, ch = t & 7;
      xr = *(const uint4*)&embB[(size_t)tokS[row*8 + s + 1]*64 + ch*8];
    }
    f32x4 acc[2][4] = {};
    #pragma unroll
    for (int kt=0;kt<4;kt++){
      short8 af[2];
      #pragma unroll
      for (int rt=0;rt<2;rt++)
        af[rt] = *(const short8*)&As[p][(rt*16+m)*GLD + kt*32 + q*8];
      #pragma unroll
      for (int j=0;j<4;j++)
        #pragma unroll
        for (int rt=0;rt<2;rt++)
          acc[rt][j] = __builtin_amdgcn_mfma_f32_16x16x32_bf16(breg[j][kt], af[rt], acc[rt][j], 0,0,0);
    }
    unsigned int plo_[2], phi_[2];
    #pragma unroll
    for (int rt=0;rt<2;rt++){
      float hv[4];
      #pragma unroll
      for (int i=0;i<4;i++){
        float xrg = acc[rt][0][i] + bv[0][i];
        float xzg = acc[rt][1][i] + bv[1][i];
        float xng = acc[rt][2][i] + bv[2][i];
        float hng = acc[rt][3][i] + bv[3][i];
        float pm = frcp_(1.f + fexp2_(1.442695041f*xrg));   // = 1 - sigmoid(xr)
        float zz = frcp_(1.f + fexp2_(-1.442695041f*xzg));  // z
        float a  = __builtin_fmaf(-pm, hng, xng);           // xn + (r-1)*hn
        float th = ftanh_(a);
        float hp = bf2f(hreg[rt][i]);
        hv[i] = __builtin_fmaf(zz, hp - th, th);            // (1-z)n + z*h
      }
      unsigned int plo = cvt_pk_bf16(hv[0], hv[1]);
      unsigned int phi = cvt_pk_bf16(hv[2], hv[3]);
      plo_[rt] = plo; phi_[rt] = phi;
      hreg[rt][0] = (unsigned short)plo;
      hreg[rt][1] = (unsigned short)(plo >> 16);
      hreg[rt][2] = (unsigned short)phi;
      hreg[rt][3] = (unsigned short)(phi >> 16);
    }
    if (s < 7){
      #pragma unroll
      for (int rt=0;rt<2;rt++){
        uint2 v; v.x = plo_[rt]; v.y = phi_[rt];
        *(uint2*)&As[p^1][(rt*16 + m)*GLD + 64 + u4] = v;   // one ds_write_b64
      }
      if (t < GRR*8){
        int row = t >> 3, ch = t & 7;
        *(uint4*)&As[p^1][row*GLD + ch*8] = xr;
      }
      __syncthreads();
      p ^= 1;
    } else {
      #pragma unroll
      for (int rt=0;rt<2;rt++){
        int nd = idxS[rt*16 + m];
        if (nd >= 0){
          size_t b = (size_t)nd*80 + 6 + u4;
          *(unsigned int*)&hOut[b]     = plo_[rt];          // 4B-aligned dword
          *(unsigned int*)&hOut[b + 2] = phi_[rt];
        }
      }
    }
  }
}

// ======== wgemm v4: grid-strided dbuf + async global_load_lds + swapped mfma ========
template<int RTR, int KT, int CT, int ACT>
__global__ __launch_bounds__(256) void wgemm(
    const unsigned short* __restrict__ A0, int w0, int ldA0,
    const unsigned short* __restrict__ A1, int w1, int ldA1,
    const unsigned short* __restrict__ A2, int w2, int ldA2,
    const unsigned short* __restrict__ Bt, int KpB,
    const float* __restrict__ bias,
    unsigned short* __restrict__ C, int ldC,
    int rows, int tiles)
{
  constexpr int Kpad = KT*32;
  constexpr int NRT  = RTR/16;
  constexpr int NCH  = KT*4;                 // 16B chunks per row
  constexpr int CPT  = (RTR*NCH)/256;        // DMA issues per thread per tile
  __shared__ __align__(16) unsigned short As[2][RTR*Kpad];
  int t = threadIdx.x;
  int lane = t & 63, m = lane & 15, q = lane >> 4, w = t >> 6;
  int tileBase = blockIdx.y * (4*CT);
  int rtEnd = (rows + RTR - 1)/RTR;
  int tr = blockIdx.x;
  if (tr >= rtEnd) return;

  short8 breg[CT][KT]; f32x4 bv[CT]; bool val[CT]; int colb[CT];
  #pragma unroll
  for (int j=0;j<CT;j++){
    int tt = tileBase + w + 4*j;
    val[j] = (tt < tiles);
    int col = tt*16 + m;
    colb[j] = tt*16 + q*4;                   // this lane's 4-col store base
    bv[j] = (f32x4){0.f,0.f,0.f,0.f};
    if (val[j]){
      bv[j] = *(const f32x4*)&bias[tt*16 + q*4];   // 16B-aligned float4
      #pragma unroll
      for (int kt=0;kt<KT;kt++)
        breg[j][kt] = *(const short8*)&Bt[(size_t)col*KpB + kt*32 + q*8];
    } else {
      #pragma unroll
      for (int kt=0;kt<KT;kt++) breg[j][kt] = (short8){0,0,0,0,0,0,0,0};
    }
  }

  int w01 = w0 + w1, w012 = w0 + w1 + w2;

  // pre-zero LDS slots whose LOGICAL chunk lies in the K-pad (msg only: Kpad>w012);
  // their DMA lanes are masked forever, so zeros persist across all tiles.
  if (w012 < NCH*8){
    const uint4 z = {0,0,0,0};
    for (int c = t; c < RTR*NCH; c += 256){
      int row = c / NCH, chp = c - row*NCH;
      if (((chp ^ (row & 3))*8) >= w012){
        *(uint4*)&As[0][c*8] = z;
        *(uint4*)&As[1][c*8] = z;
      }
    }
  }

  // async stage: per-lane source pre-swizzled, LDS dest linear (wave base + lane*16)
  auto stage = [&](int p, int trr){
    #pragma unroll
    for (int i=0;i<CPT;i++){
      int c = i*256 + t;
      int row = c / NCH, chp = c - row*NCH;
      int kc = (chp ^ (row & 3))*8;              // pre-swizzled source column
      int gr = trr*RTR + row;
      unsigned short* ldst = &As[p][(size_t)(i*256 + (t & ~63))*8];
      if (gr < rows && kc < w012){
        const unsigned short* sp;
        if (kc < w0)       sp = A0 + (size_t)gr*ldA0 + kc;
        else if (kc < w01) sp = A1 + (size_t)gr*ldA1 + (kc - w0);
        else               sp = A2 + (size_t)gr*ldA2 + (kc - w01);
        gload_lds16(sp, ldst);
      }
    }
  };

  stage(0, tr);
  __syncthreads();                                 // implicit vmcnt(0): tile 0 landed
  int p = 0;
  for (;;){
    int nxt = tr + gridDim.x;
    bool hasNext = (nxt < rtEnd);
    if (hasNext) stage(p^1, nxt);                  // DMA overlaps this tile's compute
    f32x4 acc[NRT][CT] = {};
    #pragma unroll
    for (int kt=0;kt<KT;kt++){
      short8 af[NRT];
      #pragma unroll
      for (int rt=0;rt<NRT;rt++)
        af[rt] = *(const short8*)&As[p][(rt*16+m)*Kpad + (((kt*4+q) ^ (m&3))*8)];
      #pragma unroll
      for (int j=0;j<CT;j++)
        #pragma unroll
        for (int rt=0;rt<NRT;rt++)
          acc[rt][j] = __builtin_amdgcn_mfma_f32_16x16x32_bf16(breg[j][kt], af[rt], acc[rt][j], 0,0,0);
    }
    bool tfull = (tr*RTR + RTR <= rows);
#define EPILOG(CHK)                                                         \
    _Pragma("unroll")                                                       \
    for (int rt=0;rt<NRT;rt++){                                             \
      int grow = tr*RTR + rt*16 + m;                                        \
      if (CHK && grow >= rows) continue;                                    \
      _Pragma("unroll")                                                     \
      for (int j=0;j<CT;j++){                                               \
        if (!val[j]) continue;                                              \
        float v0 = acc[rt][j][0] + bv[j][0];                                \
        float v1 = acc[rt][j][1] + bv[j][1];                                \
        float v2 = acc[rt][j][2] + bv[j][2];                                \
        float v3 = acc[rt][j][3] + bv[j][3];                                \
        if (ACT == 1){ v0=fgelu_(v0); v1=fgelu_(v1); v2=fgelu_(v2); v3=fgelu_(v3); } \
        else if (ACT == 2){ v0=ftanh_(v0); v1=ftanh_(v1); v2=ftanh_(v2); v3=ftanh_(v3); } \
        uint2 pk; pk.x = cvt_pk_bf16(v0, v1); pk.y = cvt_pk_bf16(v2, v3);   \
        *(uint2*)&C[(size_t)grow*ldC + colb[j]] = pk;                       \
      }                                                                     \
    }
    if (tfull){ EPILOG(false) } else { EPILOG(true) }
#undef EPILOG
    if (!hasNext) break;
    __syncthreads();                               // drains next-tile DMA (vmcnt 0)
    p ^= 1; tr = nxt;
  }
}

// ---------------- CSR gather + segment max v7: software-pipelined edata prefetch -----
// r10 counters: 45us, HBM 35%, VALU 38%, occ 67% -> chain-serialized, not BW-bound.
// The next quad's s_load could only issue after e+=4 (addr dependency) -> row-load
// phases of successive iterations never overlapped. Fix: prefetch gn = edata[e+4]
// WHILE this quad's row loads are in flight (addr known immediately; overrun reads
// land in edata's +16-int slack and are discarded). Successive row-load phases now
// pipeline; the chain becomes load-throughput-limited.
__global__ __launch_bounds__(256) void k_aggregate(
    const int* __restrict__ off, const int* __restrict__ bsum,
    const int* __restrict__ edata,
    const unsigned short* __restrict__ P2, int ldP, int off1,
    unsigned short* __restrict__ agg, int M, int N, int WPN)
{
  int t = threadIdx.x;
  int lane = t & 63, w = t >> 6;
  int nbase, c;
  if (WPN == 1){
    nbase = blockIdx.x*16 + w*4;                 // 16 nodes/block
    c = 2*lane;
  } else {
    nbase = blockIdx.x*8 + (w>>1)*4;             // 8 nodes/block, 2 col-half waves
    c = (w & 1)*80 + 2*lane;
  }
  nbase = __builtin_amdgcn_readfirstlane(nbase);
  if (nbase >= N) return;
  bool act = (lane < 40);
  const float NEG = -__builtin_inff();
  int e[4], e1[4];
  int4 g[4];
  float f0[4], f1[4];
  #pragma unroll
  for (int j=0;j<4;j++){
    int n = nbase + j;
    bool v = (n < N);
    e[j]  = v ? __builtin_amdgcn_readfirstlane(off[n]     + bsum[n>>11])     : 0;
    e1[j] = v ? __builtin_amdgcn_readfirstlane(off[n + 1] + bsum[(n+1)>>11]) : 0;
    f0[j] = NEG; f1[j] = NEG;
    g[j] = (e[j] < e1[j]) ? *(const int4*)&edata[e[j]] : (int4){0,0,0,0};
  }
  for (;;){
    bool cond[4];
    bool any = false;
    #pragma unroll
    for (int j=0;j<4;j++){ cond[j] = (e[j] < e1[j]); any |= cond[j]; }
    if (!any) break;
    unsigned int rr[4][4];
    #pragma unroll
    for (int j=0;j<4;j++){
      if (cond[j]){
        int b0 = (g[j].x>>1)*ldP + (g[j].x&1)*off1;    // scalar-pipe math
        int b1 = (g[j].y>>1)*ldP + (g[j].y&1)*off1;
        int b2 = (g[j].z>>1)*ldP + (g[j].z&1)*off1;
        int b3 = (g[j].w>>1)*ldP + (g[j].w&1)*off1;
        if (act){
          rr[j][0] = *(const unsigned int*)(P2 + b0 + c);
          rr[j][1] = *(const unsigned int*)(P2 + b1 + c);
          rr[j][2] = *(const unsigned int*)(P2 + b2 + c);
          rr[j][3] = *(const unsigned int*)(P2 + b3 + c);
        }
      }
    }
    int4 gn[4];
    #pragma unroll
    for (int j=0;j<4;j++){
      if (cond[j])
        gn[j] = *(const int4*)&edata[e[j] + 4];  // prefetch next quad (slack-safe)
    }
    #pragma unroll
    for (int j=0;j<4;j++){
      if (cond[j]){
        if (act){
          unsigned int u0 = rr[j][0], u1 = rr[j][1], u2 = rr[j][2], u3 = rr[j][3];
          f0[j] = fmaxf(f0[j], fmaxf(fmaxf(__uint_as_float(u0<<16), __uint_as_float(u1<<16)),
                                     fmaxf(__uint_as_float(u2<<16), __uint_as_float(u3<<16))));
          f1[j] = fmaxf(f1[j], fmaxf(fmaxf(__uint_as_float(u0&0xFFFF0000u), __uint_as_float(u1&0xFFFF0000u)),
                                     fmaxf(__uint_as_float(u2&0xFFFF0000u), __uint_as_float(u3&0xFFFF0000u))));
        }
        e[j] += 4;
        g[j] = gn[j];
      }
    }
  }
  if (act){
    #pragma unroll
    for (int j=0;j<4;j++){
      int n = nbase + j;
      if (n >= N) continue;
      unsigned int o = (__float_as_uint(f0[j] == NEG ? 0.f : f0[j]) >> 16)
                     |  (__float_as_uint(f1[j] == NEG ? 0.f : f1[j]) & 0xFFFF0000u);
      *(unsigned int*)(agg + (size_t)n*M + c) = o;
    }
  }
}

// ---------------- final head ----------------
__global__ void k_head(const unsigned short* __restrict__ h, const int* __restrict__ entry,
                       const float* __restrict__ W1, const float* __restrict__ b1,
                       const float* __restrict__ W2, const float* __restrict__ b2,
                       float* __restrict__ out){
  __shared__ float x[70], x1[70];
  int t = threadIdx.x;
  if (t < 70) x[t] = bf2f(h[(size_t)(*entry)*80 + t]);
  __syncthreads();
  if (t < 70){
    float s = b1[t];
    for (int i=0;i<70;i++) s += x[i]*W1[i*70 + t];
    x1[t] = fmaxf(s, 0.f);
  }
  __syncthreads();
  if (t < 640){
    float s = b2[t];
    for (int i=0;i<70;i++) s += x1[i]*W2[i*640 + t];
    out[t] = s;
  }
}

extern "C" void kernel_launch(void* const* d_in, const int* in_sizes, int n_in,
                              void* d_out, int out_size, void* d_ws, size_t ws_size,
                              hipStream_t stream) {
  const int*   tokens   = (const int*)d_in[0];
  const int*   type_idx = (const int*)d_in[1];
  const int*   esrc     = (const int*)d_in[2];
  const int*   edst     = (const int*)d_in[3];
  const int*   entry    = (const int*)d_in[4];
  const float* embed    = (const float*)d_in[5];
  const float* Wi_map   = (const float*)d_in[6];
  const float* Wh_map   = (const float*)d_in[7];
  const float* bi_map   = (const float*)d_in[8];
  const float* bh_map   = (const float*)d_in[9];
  const float* Wi_mem   = (const float*)d_in[10];
  const float* Wh_mem   = (const float*)d_in[11];
  const float* bi_mem   = (const float*)d_in[12];
  const float* bh_mem   = (const float*)d_in[13];
  const float* Wm_plain = (const float*)d_in[14];
  const float* bm_plain = (const float*)d_in[15];
  const float* Wu_plain = (const float*)d_in[16];
  const float* bu_plain = (const float*)d_in[17];
  const float* Wm_ar    = (const float*)d_in[18];
  const float* bm_ar    = (const float*)d_in[19];
  const float* Wu_ar    = (const float*)d_in[20];
  const float* bu_ar    = (const float*)d_in[21];
  const float* W1 = (const float*)d_in[22];
  const float* b1 = (const float*)d_in[23];
  const float* W2 = (const float*)d_in[24];
  const float* b2 = (const float*)d_in[25];
  float* out = (float*)d_out;

  const int N  = in_sizes[1];      // 100000
  const int TE = in_sizes[2];      // 500000
  const int E  = TE / 2;
  const int V64 = in_sizes[5];     // V*DE = 640000

  char* p = (char*)d_ws;
  auto alloc = [&](size_t bytes)->char* { char* r = p; p += (bytes + 255) & ~(size_t)255; return r; };
  unsigned short* hA  = (unsigned short*)alloc((size_t)N*80*2);
  unsigned short* hB  = (unsigned short*)alloc((size_t)N*80*2);
  unsigned short* hC  = (unsigned short*)alloc((size_t)N*80*2);
  unsigned short* P2  = (unsigned short*)alloc((size_t)N*320*2);
  unsigned short* agg = (unsigned short*)alloc((size_t)N*160*2);
  int* deg    = (int*)alloc((size_t)N*4);          // deg+cnt adjacent: ONE memset
  int* cnt    = (int*)alloc(16*4);
  int* curp   = (int*)alloc((size_t)N*4);
  int* off    = (int*)alloc((size_t)(N+8)*4);
  int* edata  = (int*)alloc((size_t)(TE + 4*N + 16)*4);            // x4-padded CSR
  int* sbsum  = (int*)alloc(256*4);
  int* idxcat = (int*)alloc((size_t)R2*4);
  unsigned short* BtA  = (unsigned short*)alloc(388096*2);
  float* biasA = (float*)alloc(2752*4);
  unsigned short* embB = (unsigned short*)alloc((size_t)V64*2);

  // single memset spans deg..cnt (adjacent in the arena)
  hipMemsetAsync(deg, 0, (size_t)((char*)cnt - (char*)deg) + 16*4, stream);

  // fused prep: edge-count + weights + bias + embed + init_h + curp-zero + compact
  {
    int BCnt = (TE + 255)/256;
    int BPB = 18*32, BB = 1;
    int BE  = (V64/8 + 255)/256;
    int BH  = (N*10 + 255)/256;
    int BZ  = (N/4 + 255)/256;
    int BC  = (N + 255)/256;
    int GP  = BCnt + BPB + BB + BE + BH + BZ + BC;
    k_prep_all<<<GP, 256, 0, stream>>>(
        edst, TE, deg,
        Wm_plain, Wu_plain, Wm_ar, Wu_ar, Wi_map, Wh_map, Wi_mem, Wh_mem, BtA,
        bm_plain, bu_plain, bm_ar, bu_ar, bi_map, bh_map, bi_mem, bh_mem, biasA,
        embed, embB, V64,
        type_idx, hA, N,
        curp,
        idxcat, cnt);
  }

  int nb = (N + 2047)/2048;
  k_scan1<<<nb, 256, 0, stream>>>(deg, off, sbsum, N);
  k_scan2<<<1, 64, 0, stream>>>(sbsum, off, N, nb);
  k_fill<<<(TE+255)/256, 256, 0, stream>>>(esrc, edst, off, sbsum, deg, curp, edata, TE, E);

  // ---- GRU: one persistent launch (8 steps internal), gather+scatter fused ----
  kgru<<<dim3(CAPT/GRR, 2), 256, 0, stream>>>(
      idxcat, cnt, tokens, embB,
      BtA + 322560, BtA + 322560 + 32768,
      biasA + 2240, biasA + 2240 + 256, hA);

  // ---- 2 blocks x (3 plain MP + concat-residual AR MP) ----
  unsigned short* cur = hA; unsigned short* f1 = hB; unsigned short* f2 = hC;
  int li = 0;
  for (int blk = 0; blk < 2; blk++){
    unsigned short* saved = cur;
    unsigned short* ins[3]  = {cur, f1, f2};
    unsigned short* outs[3] = {f1, f2, f1};
    for (int j = 0; j < 3; j++){
      unsigned short* X = ins[j]; unsigned short* Yo = outs[j];
      // msg: [N,80] @ [96->160] (both edge types fused in cols)
      wgemm<64,3,3,0><<<dim3(1024,1), 256, 0, stream>>>(
          X, 80, 80,  nullptr, 0, 0,  nullptr, 0, 0,
          BtA + li*15360, 96, biasA + li*160,
          P2, 160, N, 10);
      k_aggregate<<<(N+15)/16, 256, 0, stream>>>(off, sbsum, edata, P2, 160, 80, agg, 80, N, 1);
      // upd: [N,80|80] @ [160->80]
      wgemm<64,5,2,0><<<dim3(1024,1), 256, 0, stream>>>(
          X, 80, 80,  agg, 80, 80,  nullptr, 0, 0,
          BtA + 92160 + li*12800, 160, biasA + 960 + li*80,
          Yo, 80, N, 5);
      li++;
    }
    // AR msg: [N,80|80] @ [160->320], gelu; y splits 20 col tiles into 12+8
    wgemm<64,5,3,1><<<dim3(512,2), 256, 0, stream>>>(
        saved, 80, 80,  f1, 80, 80,  nullptr, 0, 0,
        BtA + 168960 + blk*51200, 160, biasA + 1440 + blk*320,
        P2, 320, N, 20);
    k_aggregate<<<(N+7)/8, 256, 0, stream>>>(off, sbsum, edata, P2, 320, 160, agg, 160, N, 2);
    // AR upd: [N,80|80|160] @ [320->80], tanh; 32-row tiles (K=320 LDS)
    wgemm<32,10,2,2><<<dim3(1024,1), 256, 0, stream>>>(
        saved, 80, 80,  f1, 80, 80,  agg, 160, 160,
        BtA + 271360 + blk*25600, 320, biasA + 2080 + blk*80,
        f2, 80, N, 5);
    unsigned short* t3 = cur; cur = f2; f2 = t3;
  }

  k_head<<<1, 640, 0, stream>>>(cur, entry, W1, b1, W2, b2, out);
}

// Round 12
// 698.827 us; speedup vs baseline: 1.0597x; 1.0597x over previous
//
#include <hip/hip_runtime.h>
#include <math.h>

#define CAPT 20480              // per-type compacted-node capacity (actual ~16.7k)
#define R2   (2*CAPT)
#define GLD  136                // kgru LDS row stride (ushorts): breaks pow2 banking
#define GRR  32                 // kgru rows per block

typedef __attribute__((ext_vector_type(8))) short short8;
typedef __attribute__((ext_vector_type(4))) float f32x4;

// ---- fast transcendentals: v_exp_f32 / v_rcp_f32 based; err ~1e-7 << bf16 ulp ----
__device__ __forceinline__ float fexp2_(float x){ return __builtin_amdgcn_exp2f(x); }
__device__ __forceinline__ float frcp_(float x){ return __builtin_amdgcn_rcpf(x); }
// tanh(x) = 1 - 2/(1+e^{2x}); overflow-safe: exp2->inf => rcp->0 => 1; underflow => -1.
__device__ __forceinline__ float ftanh_(float x){
  float t = fexp2_(2.885390082f * x);
  return __builtin_fmaf(-2.f, frcp_(1.f + t), 1.f);
}
__device__ __forceinline__ float fsig_(float x){
  return frcp_(1.f + fexp2_(-1.442695041f * x));
}
// exact rewrite of tanh-approx gelu: 0.5x(1+tanh(c(x+0.044715x^3))) == x*sigmoid(2c(x+0.044715x^3))
__device__ __forceinline__ float fgelu_(float x){
  float x2 = x*x;
  float u  = x * __builtin_fmaf(x2, 0.044715f, 1.0f);
  float e  = fexp2_(u * -2.30220818f);
  return x * frcp_(1.f + e);
}
__device__ __forceinline__ unsigned short f2bf(float x){
  unsigned int u = __float_as_uint(x);
  return (unsigned short)((u + 0x7FFFu + ((u>>16)&1u)) >> 16);
}
__device__ __forceinline__ float bf2f(unsigned short v){
  return __uint_as_float(((unsigned int)v) << 16);
}
// packed RNE f32->bf16 pair: 1 inst replaces 2x 5-op manual sequences (same rounding)
__device__ __forceinline__ unsigned int cvt_pk_bf16(float a, float b){
  unsigned int r;
  asm("v_cvt_pk_bf16_f32 %0, %1, %2" : "=v"(r) : "v"(a), "v"(b));
  return r;
}
// async global->LDS DMA, 16B per lane; dest = wave-uniform base + lane*16
__device__ __forceinline__ void gload_lds16(const unsigned short* g, unsigned short* l){
  __builtin_amdgcn_global_load_lds((const __attribute__((address_space(1))) void*)g,
                                   (__attribute__((address_space(3))) void*)l, 16, 0, 0);
}

// ======== k_prep_all v3: ALL independent prep + edge-count + curp-zero in ONE launch =
__global__ void k_prep_all(
    const int* __restrict__ edst, int TE, int* __restrict__ deg,
    const float* __restrict__ Wm_plain, const float* __restrict__ Wu_plain,
    const float* __restrict__ Wm_ar, const float* __restrict__ Wu_ar,
    const float* __restrict__ Wi_map, const float* __restrict__ Wh_map,
    const float* __restrict__ Wi_mem, const float* __restrict__ Wh_mem,
    unsigned short* __restrict__ BtArena,
    const float* __restrict__ bm_plain, const float* __restrict__ bu_plain,
    const float* __restrict__ bm_ar, const float* __restrict__ bu_ar,
    const float* __restrict__ bi_map, const float* __restrict__ bh_map,
    const float* __restrict__ bi_mem, const float* __restrict__ bh_mem,
    float* __restrict__ biasA,
    const float* __restrict__ embed, unsigned short* __restrict__ embB, int V64,
    const int* __restrict__ type_idx, unsigned short* __restrict__ h, int N,
    int* __restrict__ curp,
    int* __restrict__ idxcat, int* __restrict__ cnt)
{
  __shared__ int lc[2];
  __shared__ int lbase[2];
  int t = threadIdx.x;
  int b = blockIdx.x;
  const int BCnt = (TE + 255)/256;
  const int BPB = 18*32;
  const int BE  = (V64/8 + 255)/256;
  const int BH  = (N*10 + 255)/256;
  const int BZ  = (N/4 + 255)/256;
  int e0 = BCnt, e1 = e0 + BPB, e2 = e1 + 1, e3 = e2 + BE, e4 = e3 + BH, e5 = e4 + BZ;

  if (b < e0){
    // ---- role C: edge-count histogram (deg pre-zeroed by memset) ----
    int i = b*256 + t;
    if (i < TE) atomicAdd(&deg[edst[i]], 1);
  } else if (b < e1){
    // ---- role 0: weight arena (id = bb/32, xpart = bb%32) ----
    int bb = b - e0;
    int id = bb >> 5, xpart = bb & 31;
    int Kp, elems, off;
    if (id < 6){ Kp=96;  elems=15360; off=id*15360; }
    else if (id < 12){ Kp=160; elems=12800; off=92160+(id-6)*12800; }
    else if (id < 14){ Kp=160; elems=51200; off=168960+(id-12)*51200; }
    else if (id < 16){ Kp=320; elems=25600; off=271360+(id-14)*25600; }
    else { Kp=128; elems=32768; off=322560+(id-16)*32768; }
    for (int g = xpart*256 + t; g < elems; g += 32*256){
      int c = g / Kp, k = g - c*Kp;
      float val = 0.f;
      if (id < 6){
        int li = id; int tt = (c >= 80); int cc = c - tt*80;
        if (cc < 70 && k < 70) val = Wm_plain[((li*2+tt)*70 + k)*70 + cc];
      } else if (id < 12){
        int li = id-6;
        int kk = (k < 70) ? k : ((k >= 80 && k < 150) ? 70 + (k-80) : -1);
        if (c < 70 && kk >= 0) val = Wu_plain[(li*140 + kk)*70 + c];
      } else if (id < 14){
        int blk = id-12; int tt = (c >= 160); int cc = c - tt*160;
        int kk = (k < 70) ? k : ((k >= 80 && k < 150) ? 70 + (k-80) : -1);
        if (cc < 140 && kk >= 0) val = Wm_ar[(((blk*2+tt)*140) + kk)*140 + cc];
      } else if (id < 16){
        int blk = id-14;
        int kk = (k < 70) ? k : ((k >= 80 && k < 150) ? 70 + (k-80)
                 : ((k >= 160 && k < 300) ? 140 + (k-160) : -1));
        if (c < 70 && kk >= 0) val = Wu_ar[(blk*280 + kk)*70 + c];
      } else {
        int typ = id-16;
        const float* Wi = typ ? Wi_mem : Wi_map;
        const float* Wh = typ ? Wh_mem : Wh_map;
        if (c < 192) val = (k < 64) ? Wi[c*64 + k] : Wh[c*64 + (k-64)];
        else { int cc = c-192; val = (k >= 64) ? Wh[(128+cc)*64 + (k-64)] : 0.f; }
      }
      BtArena[off + g] = f2bf(val);
    }
  } else if (b < e2){
    // ---- role 1: bias arena ----
    for (int g = t; g < 2752; g += 256){
      float val = 0.f;
      if (g < 960){ int li=g/160, c=g%160; int tt=(c>=80); int cc=c-tt*80;
        if (cc<70) val = bm_plain[(li*2+tt)*70 + cc]; }
      else if (g < 1440){ int u=g-960; int li=u/80, c=u%80; if (c<70) val = bu_plain[li*70+c]; }
      else if (g < 2080){ int u=g-1440; int blk=u/320, c=u%320; int tt=(c>=160); int cc=c-tt*160;
        if (cc<140) val = bm_ar[(blk*2+tt)*140 + cc]; }
      else if (g < 2240){ int u=g-2080; int blk=u/80, c=u%80; if (c<70) val = bu_ar[blk*70+c]; }
      else { int u=g-2240; int typ=u/256, c=u%256;
        const float* bi = typ ? bi_mem : bi_map; const float* bh = typ ? bh_mem : bh_map;
        val = (c < 192) ? (bi[c]+bh[c]) : bh[128 + (c-192)]; }
      biasA[g] = val;
    }
  } else if (b < e3){
    // ---- role 2: embed -> bf16, 8 elems/thread ----
    int g = (b - e2)*256 + t;
    if (g < V64/8){
      const float* s = embed + (size_t)g*8;
      unsigned int p0 = cvt_pk_bf16(s[0], s[1]);
      unsigned int p1 = cvt_pk_bf16(s[2], s[3]);
      unsigned int p2 = cvt_pk_bf16(s[4], s[5]);
      unsigned int p3 = cvt_pk_bf16(s[6], s[7]);
      uint4 v = {p0, p1, p2, p3};
      *(uint4*)&embB[(size_t)g*8] = v;
    }
  } else if (b < e4){
    // ---- role 3: init h one-hot, 8 bf16/thread (10 threads per 80-wide row) ----
    int g = (b - e3)*256 + t;
    if (g < N*10){
      int n = g / 10, c0 = (g - n*10)*8;
      unsigned int w0 = 0, w1 = 0, w2 = 0, w3 = 0;
      if (c0 == 0){
        int ty = type_idx[n];
        unsigned int one = 0x3F80u;
        if (ty == 0) w0 |= one;        else if (ty == 1) w0 |= one << 16;
        if (ty == 2) w1 |= one;        else if (ty == 3) w1 |= one << 16;
        if (ty == 4) w2 |= one;        else if (ty == 5) w2 |= one << 16;
      }
      uint4 v = {w0, w1, w2, w3};
      *(uint4*)&h[(size_t)n*80 + c0] = v;
    }
  } else if (b < e5){
    // ---- role 4: zero curp (int4/thread; read only by k_fill, 3 dispatches later) ----
    int g = (b - e4)*256 + t;
    if (g < N/4){
      const int4 z = {0,0,0,0};
      *(int4*)&curp[g*4] = z;
    }
    if (g == 0){
      for (int r = (N/4)*4; r < N; r++) curp[r] = 0;     // tail (N%4)
    }
  } else {
    // ---- role 5: compact, LDS-aggregated (1 global atomic per block per type) ----
    if (t < 2) lc[t] = 0;
    __syncthreads();
    int n = (b - e5)*256 + t;
    int sel = -1, pos = 0;
    if (n < N){
      int ty = type_idx[n];
      if (ty == 0){ sel = 0; pos = atomicAdd(&lc[0], 1); }
      else if (ty == 5){ sel = 1; pos = atomicAdd(&lc[1], 1); }
    }
    __syncthreads();
    if (t < 2) lbase[t] = lc[t] ? atomicAdd(&cnt[t], lc[t]) : 0;
    __syncthreads();
    if (sel >= 0){
      int p = lbase[sel] + pos;
      if (p < CAPT) idxcat[sel*CAPT + p] = n;
    }
  }
}

// ---------------- CSR build: scan1 (per-chunk partial offsets) + scan2 (chunk prefix)
__global__ void k_scan1(const int* __restrict__ deg, int* __restrict__ off,
                        int* __restrict__ bsum, int N){
  __shared__ int sh[256];
  int t = threadIdx.x; int base = blockIdx.x*2048;
  int v[8]; int s = 0;
  for (int i=0;i<8;i++){
    int g = base + t*8 + i;
    int x = (g<N)? (((deg[g]+3)>>2)<<2) : 0;     // pad to x4
    v[i]=x; s+=x;
  }
  sh[t]=s; __syncthreads();
  for (int o=1;o<256;o<<=1){ int x = (t>=o)? sh[t-o]:0; __syncthreads(); sh[t]+=x; __syncthreads(); }
  if (t==255) bsum[blockIdx.x] = sh[255];
  int run = sh[t]-s;
  for (int i=0;i<8;i++){ int g = base + t*8 + i; if (g<N) off[g]=run; run+=v[i]; }
}
// converts bsum to prefix AND closes the last node's range: off[N]+bsum[N>>11] == total
__global__ void k_scan2(int* bsum, int* off, int N, int nb){
  if (threadIdx.x==0 && blockIdx.x==0){
    int run=0;
    for(int b=0;b<nb;b++){ int x=bsum[b]; bsum[b]=run; run+=x; }
    bsum[nb]=run;
    off[N] = run - bsum[N>>11];
  }
}
// fill + SELF-PAD: the thread placing a node's LAST edge writes the pad slots with its
// OWN edge (idempotent for segment-max; messages depend only on (src,type)).
__global__ void k_fill(const int* __restrict__ esrc, const int* __restrict__ edst,
                       const int* __restrict__ off, const int* __restrict__ bsum,
                       const int* __restrict__ deg, int* __restrict__ cur,
                       int* __restrict__ edata, int TE, int E){
  int i = blockIdx.x*256 + threadIdx.x;
  if (i >= TE) return;
  int d = edst[i];
  int pos = atomicAdd(&cur[d], 1);
  int base = off[d] + bsum[d>>11];
  int ev = (esrc[i] << 1) | (i >= E ? 1 : 0);
  edata[base + pos] = ev;
  int dg = deg[d];
  if (pos == dg - 1){
    int d4 = ((dg+3)>>2)<<2;
    for (int k = dg; k < d4; k++) edata[base + k] = ev;
  }
}

// ======== kgru v6: count-based validity (no idxcat sentinel memset needed) ==========
__global__ __launch_bounds__(256) void kgru(
    const int* __restrict__ idxcat, const int* __restrict__ cnt,
    const int* __restrict__ tokens,
    const unsigned short* __restrict__ embB,
    const unsigned short* __restrict__ Bt, const unsigned short* __restrict__ Bt2,
    const float* __restrict__ bias, const float* __restrict__ bias2,
    unsigned short* __restrict__ hOut)
{
  __shared__ __align__(16) unsigned short As[2][GRR*GLD];
  __shared__ int tokS[GRR*8];
  __shared__ int idxS[GRR];
  int nv = cnt[blockIdx.y]; if (nv > CAPT) nv = CAPT;
  int r0 = blockIdx.x * GRR;
  if (r0 >= nv) return;                            // fully-invalid block
  int rb = blockIdx.y * CAPT + r0;
  int t = threadIdx.x;
  int lane = t & 63, m = lane & 15, q = lane >> 4, w = t >> 6;
  const unsigned short* Bsel = blockIdx.y ? Bt2 : Bt;
  const float* bsel = blockIdx.y ? bias2 : bias;
  short8 breg[4][4]; f32x4 bv[4];
  #pragma unroll
  for (int j=0;j<4;j++){
    int col = (w + 4*j)*16 + m;
    bv[j] = *(const f32x4*)&bsel[(w + 4*j)*16 + q*4];   // 16B-aligned float4
    #pragma unroll
    for (int kt=0;kt<4;kt++)
      breg[j][kt] = *(const short8*)&Bsel[(size_t)col*128 + kt*32 + q*8];
  }
  if (t < GRR) idxS[t] = (r0 + t < nv) ? idxcat[rb + t] : -1;
  if (t < GRR*8){
    int r8 = t >> 3;
    int nd = (r0 + r8 < nv) ? idxcat[rb + r8] : 0;
    if (nd < 0) nd = 0;
    tokS[t] = tokens[nd*8 + (t & 7)];
  }
  __syncthreads();                                 // tokS ready
  if (t < GRR*8){
    int row = t >> 3, ch = t & 7;
    *(uint4*)&As[0][row*GLD + ch*8] = *(const uint4*)&embB[(size_t)tokS[row*8]*64 + ch*8];
  }
  for (int j = t; j < GRR*32; j += 256){
    int row = j >> 5, k2 = (j & 31)*2;
    *(unsigned int*)&As[0][row*GLD + 64 + k2] = 0;
  }
  __syncthreads();
  unsigned short hreg[2][4];                       // row m (per rt), cols u4+0..3
  #pragma unroll
  for (int rt=0;rt<2;rt++)
    #pragma unroll
    for (int i=0;i<4;i++) hreg[rt][i] = 0;
  int u4 = w*16 + q*4;                             // col base within H (64 wide)
  int p = 0;
  for (int s = 0; s < 8; s++){
    uint4 xr;
    if (s < 7 && t < GRR*8){                       // prefetch X(s+1) early (global)
      int row = t >> 3, ch = t & 7;
      xr = *(const uint4*)&embB[(size_t)tokS[row*8 + s + 1]*64 + ch*8];
    }
    f32x4 acc[2][4] = {};
    #pragma unroll
    for (int kt=0;kt<4;kt++){
      short8 af[2];
      #pragma unroll
      for (int rt=0;rt<2;rt++)
        af[rt] = *(const short8*)&As[p][(rt*16+m)*GLD + kt*32 + q*8];
      #pragma unroll
      for (int j=0;j<4;j++)
        #pragma unroll
        for (int rt=0;rt<2;rt++)
          acc[rt][j] = __builtin_amdgcn_mfma_f32_16x16x32_bf16(breg[j][kt], af[rt], acc[rt][j], 0,0,0);
    }
    unsigned int plo_[2], phi_[2];
    #pragma unroll
    for (int rt=0;rt<2;rt++){
      float hv[4];
      #pragma unroll
      for (int i=0;i<4;i++){
        float xrg = acc[rt][0][i] + bv[0][i];
        float xzg = acc[rt][1][i] + bv[1][i];
        float xng = acc[rt][2][i] + bv[2][i];
        float hng = acc[rt][3][i] + bv[3][i];
        float pm = frcp_(1.f + fexp2_(1.442695041f*xrg));   // = 1 - sigmoid(xr)
        float zz = frcp_(1.f + fexp2_(-1.442695041f*xzg));  // z
        float a  = __builtin_fmaf(-pm, hng, xng);           // xn + (r-1)*hn
        float th = ftanh_(a);
        float hp = bf2f(hreg[rt][i]);
        hv[i] = __builtin_fmaf(zz, hp - th, th);            // (1-z)n + z*h
      }
      unsigned int plo = cvt_pk_bf16(hv[0], hv[1]);
      unsigned int phi = cvt_pk_bf16(hv[2], hv[3]);
      plo_[rt] = plo; phi_[rt] = phi;
      hreg[rt][0] = (unsigned short)plo;
      hreg[rt][1] = (unsigned short)(plo >> 16);
      hreg[rt][2] = (unsigned short)phi;
      hreg[rt][3] = (unsigned short)(phi >> 16);
    }
    if (s < 7){
      #pragma unroll
      for (int rt=0;rt<2;rt++){
        uint2 v; v.x = plo_[rt]; v.y = phi_[rt];
        *(uint2*)&As[p^1][(rt*16 + m)*GLD + 64 + u4] = v;   // one ds_write_b64
      }
      if (t < GRR*8){
        int row = t >> 3, ch = t & 7;
        *(uint4*)&As[p^1][row*GLD + ch*8] = xr;
      }
      __syncthreads();
      p ^= 1;
    } else {
      #pragma unroll
      for (int rt=0;rt<2;rt++){
        int nd = idxS[rt*16 + m];
        if (nd >= 0){
          size_t b = (size_t)nd*80 + 6 + u4;
          *(unsigned int*)&hOut[b]     = plo_[rt];          // 4B-aligned dword
          *(unsigned int*)&hOut[b + 2] = phi_[rt];
        }
      }
    }
  }
}

// ======== wgemm v4: grid-strided dbuf + async global_load_lds + swapped mfma ========
template<int RTR, int KT, int CT, int ACT>
__global__ __launch_bounds__(256) void wgemm(
    const unsigned short* __restrict__ A0, int w0, int ldA0,
    const unsigned short* __restrict__ A1, int w1, int ldA1,
    const unsigned short* __restrict__ A2, int w2, int ldA2,
    const unsigned short* __restrict__ Bt, int KpB,
    const float* __restrict__ bias,
    unsigned short* __restrict__ C, int ldC,
    int rows, int tiles)
{
  constexpr int Kpad = KT*32;
  constexpr int NRT  = RTR/16;
  constexpr int NCH  = KT*4;                 // 16B chunks per row
  constexpr int CPT  = (RTR*NCH)/256;        // DMA issues per thread per tile
  __shared__ __align__(16) unsigned short As[2][RTR*Kpad];
  int t = threadIdx.x;
  int lane = t & 63, m = lane & 15, q = lane >> 4, w = t >> 6;
  int tileBase = blockIdx.y * (4*CT);
  int rtEnd = (rows + RTR - 1)/RTR;
  int tr = blockIdx.x;
  if (tr >= rtEnd) return;

  short8 breg[CT][KT]; f32x4 bv[CT]; bool val[CT]; int colb[CT];
  #pragma unroll
  for (int j=0;j<CT;j++){
    int tt = tileBase + w + 4*j;
    val[j] = (tt < tiles);
    int col = tt*16 + m;
    colb[j] = tt*16 + q*4;                   // this lane's 4-col store base
    bv[j] = (f32x4){0.f,0.f,0.f,0.f};
    if (val[j]){
      bv[j] = *(const f32x4*)&bias[tt*16 + q*4];   // 16B-aligned float4
      #pragma unroll
      for (int kt=0;kt<KT;kt++)
        breg[j][kt] = *(const short8*)&Bt[(size_t)col*KpB + kt*32 + q*8];
    } else {
      #pragma unroll
      for (int kt=0;kt<KT;kt++) breg[j][kt] = (short8){0,0,0,0,0,0,0,0};
    }
  }

  int w01 = w0 + w1, w012 = w0 + w1 + w2;

  // pre-zero LDS slots whose LOGICAL chunk lies in the K-pad (msg only: Kpad>w012);
  // their DMA lanes are masked forever, so zeros persist across all tiles.
  if (w012 < NCH*8){
    const uint4 z = {0,0,0,0};
    for (int c = t; c < RTR*NCH; c += 256){
      int row = c / NCH, chp = c - row*NCH;
      if (((chp ^ (row & 3))*8) >= w012){
        *(uint4*)&As[0][c*8] = z;
        *(uint4*)&As[1][c*8] = z;
      }
    }
  }

  // async stage: per-lane source pre-swizzled, LDS dest linear (wave base + lane*16)
  auto stage = [&](int p, int trr){
    #pragma unroll
    for (int i=0;i<CPT;i++){
      int c = i*256 + t;
      int row = c / NCH, chp = c - row*NCH;
      int kc = (chp ^ (row & 3))*8;              // pre-swizzled source column
      int gr = trr*RTR + row;
      unsigned short* ldst = &As[p][(size_t)(i*256 + (t & ~63))*8];
      if (gr < rows && kc < w012){
        const unsigned short* sp;
        if (kc < w0)       sp = A0 + (size_t)gr*ldA0 + kc;
        else if (kc < w01) sp = A1 + (size_t)gr*ldA1 + (kc - w0);
        else               sp = A2 + (size_t)gr*ldA2 + (kc - w01);
        gload_lds16(sp, ldst);
      }
    }
  };

  stage(0, tr);
  __syncthreads();                                 // implicit vmcnt(0): tile 0 landed
  int p = 0;
  for (;;){
    int nxt = tr + gridDim.x;
    bool hasNext = (nxt < rtEnd);
    if (hasNext) stage(p^1, nxt);                  // DMA overlaps this tile's compute
    f32x4 acc[NRT][CT] = {};
    #pragma unroll
    for (int kt=0;kt<KT;kt++){
      short8 af[NRT];
      #pragma unroll
      for (int rt=0;rt<NRT;rt++)
        af[rt] = *(const short8*)&As[p][(rt*16+m)*Kpad + (((kt*4+q) ^ (m&3))*8)];
      #pragma unroll
      for (int j=0;j<CT;j++)
        #pragma unroll
        for (int rt=0;rt<NRT;rt++)
          acc[rt][j] = __builtin_amdgcn_mfma_f32_16x16x32_bf16(breg[j][kt], af[rt], acc[rt][j], 0,0,0);
    }
    bool tfull = (tr*RTR + RTR <= rows);
#define EPILOG(CHK)                                                         \
    _Pragma("unroll")                                                       \
    for (int rt=0;rt<NRT;rt++){                                             \
      int grow = tr*RTR + rt*16 + m;                                        \
      if (CHK && grow >= rows) continue;                                    \
      _Pragma("unroll")                                                     \
      for (int j=0;j<CT;j++){                                               \
        if (!val[j]) continue;                                              \
        float v0 = acc[rt][j][0] + bv[j][0];                                \
        float v1 = acc[rt][j][1] + bv[j][1];                                \
        float v2 = acc[rt][j][2] + bv[j][2];                                \
        float v3 = acc[rt][j][3] + bv[j][3];                                \
        if (ACT == 1){ v0=fgelu_(v0); v1=fgelu_(v1); v2=fgelu_(v2); v3=fgelu_(v3); } \
        else if (ACT == 2){ v0=ftanh_(v0); v1=ftanh_(v1); v2=ftanh_(v2); v3=ftanh_(v3); } \
        uint2 pk; pk.x = cvt_pk_bf16(v0, v1); pk.y = cvt_pk_bf16(v2, v3);   \
        *(uint2*)&C[(size_t)grow*ldC + colb[j]] = pk;                       \
      }                                                                     \
    }
    if (tfull){ EPILOG(false) } else { EPILOG(true) }
#undef EPILOG
    if (!hasNext) break;
    __syncthreads();                               // drains next-tile DMA (vmcnt 0)
    p ^= 1; tr = nxt;
  }
}

// ---------------- CSR gather + segment max v4 (r10-proven): load-at-use quads --------
// r11 post-mortem: prefetched edata quads (SGPR-resident g/gn + conditional scalar
// loads) LENGTHENED the scalar-pipe critical path (45->50us). The load-at-use form
// lets the compiler emit one tight s_load -> addr -> v_load sequence per iteration.
__global__ __launch_bounds__(256) void k_aggregate(
    const int* __restrict__ off, const int* __restrict__ bsum,
    const int* __restrict__ edata,
    const unsigned short* __restrict__ P2, int ldP, int off1,
    unsigned short* __restrict__ agg, int M, int N, int WPN)
{
  int t = threadIdx.x;
  int lane = t & 63, w = t >> 6;
  int nbase, c;
  if (WPN == 1){
    nbase = blockIdx.x*16 + w*4;                 // 16 nodes/block
    c = 2*lane;
  } else {
    nbase = blockIdx.x*8 + (w>>1)*4;             // 8 nodes/block, 2 col-half waves
    c = (w & 1)*80 + 2*lane;
  }
  nbase = __builtin_amdgcn_readfirstlane(nbase);
  if (nbase >= N) return;
  bool act = (lane < 40);
  const float NEG = -__builtin_inff();
  int e[4], e1[4];
  float f0[4], f1[4];
  #pragma unroll
  for (int j=0;j<4;j++){
    int n = nbase + j;
    bool v = (n < N);
    e[j]  = v ? __builtin_amdgcn_readfirstlane(off[n]     + bsum[n>>11])     : 0;
    e1[j] = v ? __builtin_amdgcn_readfirstlane(off[n + 1] + bsum[(n+1)>>11]) : 0;
    f0[j] = NEG; f1[j] = NEG;
  }
  for (;;){
    bool cond[4];
    bool any = false;
    #pragma unroll
    for (int j=0;j<4;j++){ cond[j] = (e[j] < e1[j]); any |= cond[j]; }
    if (!any) break;
    unsigned int rr[4][4];
    #pragma unroll
    for (int j=0;j<4;j++){
      if (cond[j]){
        int4 g = *(const int4*)&edata[e[j]];     // uniform addr -> s_load_dwordx4
        int b0 = (g.x>>1)*ldP + (g.x&1)*off1;    // scalar-pipe math
        int b1 = (g.y>>1)*ldP + (g.y&1)*off1;
        int b2 = (g.z>>1)*ldP + (g.z&1)*off1;
        int b3 = (g.w>>1)*ldP + (g.w&1)*off1;
        if (act){
          rr[j][0] = *(const unsigned int*)(P2 + b0 + c);
          rr[j][1] = *(const unsigned int*)(P2 + b1 + c);
          rr[j][2] = *(const unsigned int*)(P2 + b2 + c);
          rr[j][3] = *(const unsigned int*)(P2 + b3 + c);
        }
      }
    }
    #pragma unroll
    for (int j=0;j<4;j++){
      if (cond[j]){
        if (act){
          unsigned int u0 = rr[j][0], u1 = rr[j][1], u2 = rr[j][2], u3 = rr[j][3];
          f0[j] = fmaxf(f0[j], fmaxf(fmaxf(__uint_as_float(u0<<16), __uint_as_float(u1<<16)),
                                     fmaxf(__uint_as_float(u2<<16), __uint_as_float(u3<<16))));
          f1[j] = fmaxf(f1[j], fmaxf(fmaxf(__uint_as_float(u0&0xFFFF0000u), __uint_as_float(u1&0xFFFF0000u)),
                                     fmaxf(__uint_as_float(u2&0xFFFF0000u), __uint_as_float(u3&0xFFFF0000u))));
        }
        e[j] += 4;
      }
    }
  }
  if (act){
    #pragma unroll
    for (int j=0;j<4;j++){
      int n = nbase + j;
      if (n >= N) continue;
      unsigned int o = (__float_as_uint(f0[j] == NEG ? 0.f : f0[j]) >> 16)
                     |  (__float_as_uint(f1[j] == NEG ? 0.f : f1[j]) & 0xFFFF0000u);
      *(unsigned int*)(agg + (size_t)n*M + c) = o;
    }
  }
}

// ---------------- final head ----------------
__global__ void k_head(const unsigned short* __restrict__ h, const int* __restrict__ entry,
                       const float* __restrict__ W1, const float* __restrict__ b1,
                       const float* __restrict__ W2, const float* __restrict__ b2,
                       float* __restrict__ out){
  __shared__ float x[70], x1[70];
  int t = threadIdx.x;
  if (t < 70) x[t] = bf2f(h[(size_t)(*entry)*80 + t]);
  __syncthreads();
  if (t < 70){
    float s = b1[t];
    for (int i=0;i<70;i++) s += x[i]*W1[i*70 + t];
    x1[t] = fmaxf(s, 0.f);
  }
  __syncthreads();
  if (t < 640){
    float s = b2[t];
    for (int i=0;i<70;i++) s += x1[i]*W2[i*640 + t];
    out[t] = s;
  }
}

extern "C" void kernel_launch(void* const* d_in, const int* in_sizes, int n_in,
                              void* d_out, int out_size, void* d_ws, size_t ws_size,
                              hipStream_t stream) {
  const int*   tokens   = (const int*)d_in[0];
  const int*   type_idx = (const int*)d_in[1];
  const int*   esrc     = (const int*)d_in[2];
  const int*   edst     = (const int*)d_in[3];
  const int*   entry    = (const int*)d_in[4];
  const float* embed    = (const float*)d_in[5];
  const float* Wi_map   = (const float*)d_in[6];
  const float* Wh_map   = (const float*)d_in[7];
  const float* bi_map   = (const float*)d_in[8];
  const float* bh_map   = (const float*)d_in[9];
  const float* Wi_mem   = (const float*)d_in[10];
  const float* Wh_mem   = (const float*)d_in[11];
  const float* bi_mem   = (const float*)d_in[12];
  const float* bh_mem   = (const float*)d_in[13];
  const float* Wm_plain = (const float*)d_in[14];
  const float* bm_plain = (const float*)d_in[15];
  const float* Wu_plain = (const float*)d_in[16];
  const float* bu_plain = (const float*)d_in[17];
  const float* Wm_ar    = (const float*)d_in[18];
  const float* bm_ar    = (const float*)d_in[19];
  const float* Wu_ar    = (const float*)d_in[20];
  const float* bu_ar    = (const float*)d_in[21];
  const float* W1 = (const float*)d_in[22];
  const float* b1 = (const float*)d_in[23];
  const float* W2 = (const float*)d_in[24];
  const float* b2 = (const float*)d_in[25];
  float* out = (float*)d_out;

  const int N  = in_sizes[1];      // 100000
  const int TE = in_sizes[2];      // 500000
  const int E  = TE / 2;
  const int V64 = in_sizes[5];     // V*DE = 640000

  char* p = (char*)d_ws;
  auto alloc = [&](size_t bytes)->char* { char* r = p; p += (bytes + 255) & ~(size_t)255; return r; };
  unsigned short* hA  = (unsigned short*)alloc((size_t)N*80*2);
  unsigned short* hB  = (unsigned short*)alloc((size_t)N*80*2);
  unsigned short* hC  = (unsigned short*)alloc((size_t)N*80*2);
  unsigned short* P2  = (unsigned short*)alloc((size_t)N*320*2);
  unsigned short* agg = (unsigned short*)alloc((size_t)N*160*2);
  int* deg    = (int*)alloc((size_t)N*4);          // deg+cnt adjacent: ONE memset
  int* cnt    = (int*)alloc(16*4);
  int* curp   = (int*)alloc((size_t)N*4);
  int* off    = (int*)alloc((size_t)(N+8)*4);
  int* edata  = (int*)alloc((size_t)(TE + 4*N + 16)*4);            // x4-padded CSR
  int* sbsum  = (int*)alloc(256*4);
  int* idxcat = (int*)alloc((size_t)R2*4);
  unsigned short* BtA  = (unsigned short*)alloc(388096*2);
  float* biasA = (float*)alloc(2752*4);
  unsigned short* embB = (unsigned short*)alloc((size_t)V64*2);

  // single memset spans deg..cnt (adjacent in the arena)
  hipMemsetAsync(deg, 0, (size_t)((char*)cnt - (char*)deg) + 16*4, stream);

  // fused prep: edge-count + weights + bias + embed + init_h + curp-zero + compact
  {
    int BCnt = (TE + 255)/256;
    int BPB = 18*32, BB = 1;
    int BE  = (V64/8 + 255)/256;
    int BH  = (N*10 + 255)/256;
    int BZ  = (N/4 + 255)/256;
    int BC  = (N + 255)/256;
    int GP  = BCnt + BPB + BB + BE + BH + BZ + BC;
    k_prep_all<<<GP, 256, 0, stream>>>(
        edst, TE, deg,
        Wm_plain, Wu_plain, Wm_ar, Wu_ar, Wi_map, Wh_map, Wi_mem, Wh_mem, BtA,
        bm_plain, bu_plain, bm_ar, bu_ar, bi_map, bh_map, bi_mem, bh_mem, biasA,
        embed, embB, V64,
        type_idx, hA, N,
        curp,
        idxcat, cnt);
  }

  int nb = (N + 2047)/2048;
  k_scan1<<<nb, 256, 0, stream>>>(deg, off, sbsum, N);
  k_scan2<<<1, 64, 0, stream>>>(sbsum, off, N, nb);
  k_fill<<<(TE+255)/256, 256, 0, stream>>>(esrc, edst, off, sbsum, deg, curp, edata, TE, E);

  // ---- GRU: one persistent launch (8 steps internal), gather+scatter fused ----
  kgru<<<dim3(CAPT/GRR, 2), 256, 0, stream>>>(
      idxcat, cnt, tokens, embB,
      BtA + 322560, BtA + 322560 + 32768,
      biasA + 2240, biasA + 2240 + 256, hA);

  // ---- 2 blocks x (3 plain MP + concat-residual AR MP) ----
  unsigned short* cur = hA; unsigned short* f1 = hB; unsigned short* f2 = hC;
  int li = 0;
  for (int blk = 0; blk < 2; blk++){
    unsigned short* saved = cur;
    unsigned short* ins[3]  = {cur, f1, f2};
    unsigned short* outs[3] = {f1, f2, f1};
    for (int j = 0; j < 3; j++){
      unsigned short* X = ins[j]; unsigned short* Yo = outs[j];
      // msg: [N,80] @ [96->160] (both edge types fused in cols)
      wgemm<64,3,3,0><<<dim3(1024,1), 256, 0, stream>>>(
          X, 80, 80,  nullptr, 0, 0,  nullptr, 0, 0,
          BtA + li*15360, 96, biasA + li*160,
          P2, 160, N, 10);
      k_aggregate<<<(N+15)/16, 256, 0, stream>>>(off, sbsum, edata, P2, 160, 80, agg, 80, N, 1);
      // upd: [N,80|80] @ [160->80]
      wgemm<64,5,2,0><<<dim3(1024,1), 256, 0, stream>>>(
          X, 80, 80,  agg, 80, 80,  nullptr, 0, 0,
          BtA + 92160 + li*12800, 160, biasA + 960 + li*80,
          Yo, 80, N, 5);
      li++;
    }
    // AR msg: [N,80|80] @ [160->320], gelu; y splits 20 col tiles into 12+8
    wgemm<64,5,3,1><<<dim3(512,2), 256, 0, stream>>>(
        saved, 80, 80,  f1, 80, 80,  nullptr, 0, 0,
        BtA + 168960 + blk*51200, 160, biasA + 1440 + blk*320,
        P2, 320, N, 20);
    k_aggregate<<<(N+7)/8, 256, 0, stream>>>(off, sbsum, edata, P2, 320, 160, agg, 160, N, 2);
    // AR upd: [N,80|80|160] @ [320->80], tanh; 32-row tiles (K=320 LDS)
    wgemm<32,10,2,2><<<dim3(1024,1), 256, 0, stream>>>(
        saved, 80, 80,  f1, 80, 80,  agg, 160, 160,
        BtA + 271360 + blk*25600, 320, biasA + 2080 + blk*80,
        f2, 80, N, 5);
    unsigned short* t3 = cur; cur = f2; f2 = t3;
  }

  k_head<<<1, 640, 0, stream>>>(cur, entry, W1, b1, W2, b2, out);
}